// Round 2
// baseline (915.589 us; speedup 1.0000x reference)
//
#include <hip/hip_runtime.h>
#include <hip/hip_bf16.h>

typedef __hip_bfloat16 bf16;
typedef __bf16 bf16x8 __attribute__((ext_vector_type(8)));
typedef float f32x4 __attribute__((ext_vector_type(4)));

static_assert(sizeof(bf16) == 2, "bf16 must be 2 bytes");

__device__ __forceinline__ float silu_f(float v) { return v / (1.0f + __expf(-v)); }

__device__ __forceinline__ void gload16(const bf16* g, bf16* l) {
  __builtin_amdgcn_global_load_lds((const __attribute__((address_space(1))) void*)g,
                                   (__attribute__((address_space(3))) void*)l,
                                   16, 0, 0);
}

// ---------------- f32 -> bf16 convert ----------------
__global__ __launch_bounds__(256) void f2b_kernel(const float* __restrict__ in,
                                                  bf16* __restrict__ out, int n) {
  int i = (blockIdx.x * 256 + threadIdx.x) * 4;
  if (i + 3 < n) {
    float4 v = *reinterpret_cast<const float4*>(in + i);
    bf16 a = __float2bfloat16(v.x), b = __float2bfloat16(v.y),
         c = __float2bfloat16(v.z), d = __float2bfloat16(v.w);
    ushort4 s;
    s.x = __builtin_bit_cast(unsigned short, a);
    s.y = __builtin_bit_cast(unsigned short, b);
    s.z = __builtin_bit_cast(unsigned short, c);
    s.w = __builtin_bit_cast(unsigned short, d);
    *reinterpret_cast<ushort4*>(out + i) = s;
  }
}

// ---------------- MFMA GEMM, C[M,N] = A[M,K] * B[N,K]^T  (both K-contiguous) ----------------
// EPI: 0 = +bias[n], write X3t shifted-triple bf16 (conv operand build)
//      1 = +bias[n], silu, f32 out   (unused)
//      2 = +bias[m], silu, bf16 out (+batch offset via sOz)
//      3 = plain f32 out
//      4 = +bias[n], f32 out
template <int EPI, int BN>
__global__ __launch_bounds__(256) void gemm_nt(const bf16* __restrict__ A,
                                               const bf16* __restrict__ Bw,
                                               const float* __restrict__ bias,
                                               float* __restrict__ outf,
                                               bf16* __restrict__ outb,
                                               int M, int N, int K,
                                               long sAz, long sBz, long sOz) {
  constexpr int BM = 128, BK = 64;
  constexpr int WNF = BN / 32;  // 16x16 frags per wave along N
  __shared__ __align__(16) bf16 As[BM * BK];
  __shared__ __align__(16) bf16 Bs[BN * BK];

  const int tid = threadIdx.x;
  const int w = tid >> 6, l = tid & 63;
  const int wm = w >> 1, wn = w & 1;
  const int m0 = blockIdx.x * BM, n0 = blockIdx.y * BN;
  const int z = blockIdx.z;
  const bf16* Ab = A + (long)z * sAz + (long)m0 * K;
  const bf16* Bb = Bw + (long)z * sBz + (long)n0 * K;

  f32x4 acc[4][WNF];
#pragma unroll
  for (int i = 0; i < 4; ++i)
#pragma unroll
    for (int j = 0; j < WNF; ++j) acc[i][j] = (f32x4){0.f, 0.f, 0.f, 0.f};

  constexpr int APW = (BM * BK / 512) / 4;  // A stage issues per wave (=4)
  constexpr int BPW = (BN * BK / 512) / 4;  // B stage issues per wave (4 or 2)

  for (int k0 = 0; k0 < K; k0 += BK) {
#pragma unroll
    for (int j = 0; j < APW; ++j) {
      int iss = w * APW + j;
      int e = iss * 512 + l * 8;
      gload16(Ab + (long)(e >> 6) * K + k0 + (e & 63), &As[iss * 512]);
    }
#pragma unroll
    for (int j = 0; j < BPW; ++j) {
      int iss = w * BPW + j;
      int e = iss * 512 + l * 8;
      gload16(Bb + (long)(e >> 6) * K + k0 + (e & 63), &Bs[iss * 512]);
    }
    __syncthreads();
    const int lr = l & 15;
#pragma unroll
    for (int kk = 0; kk < BK; kk += 32) {
      const int lk = (l >> 4) * 8 + kk;
      bf16x8 af[4], bfg[WNF];
#pragma unroll
      for (int mi = 0; mi < 4; ++mi)
        af[mi] = *reinterpret_cast<const bf16x8*>(&As[(wm * 64 + mi * 16 + lr) * BK + lk]);
#pragma unroll
      for (int ni = 0; ni < WNF; ++ni)
        bfg[ni] = *reinterpret_cast<const bf16x8*>(&Bs[(wn * (BN / 2) + ni * 16 + lr) * BK + lk]);
#pragma unroll
      for (int mi = 0; mi < 4; ++mi)
#pragma unroll
        for (int ni = 0; ni < WNF; ++ni)
          acc[mi][ni] = __builtin_amdgcn_mfma_f32_16x16x32_bf16(af[mi], bfg[ni], acc[mi][ni], 0, 0, 0);
    }
    __syncthreads();
  }

  // epilogue: D mapping col = lane&15, row = (lane>>4)*4 + j  [verified m89/m91]
  const int lr = l & 15, lq = l >> 4;
#pragma unroll
  for (int mi = 0; mi < 4; ++mi) {
#pragma unroll
    for (int ni = 0; ni < WNF; ++ni) {
#pragma unroll
      for (int j = 0; j < 4; ++j) {
        int m = m0 + wm * 64 + mi * 16 + lq * 4 + j;
        int n = n0 + wn * (BN / 2) + ni * 16 + lr;
        float v = acc[mi][ni][j];
        if (EPI == 0) {
          v += bias[n];
          bf16 vb = __float2bfloat16(v);
          bf16* Xb = outb + (long)(m >> 10) * (512L * 3072);
          int li = m & 1023;
          int d = n;
          // X3t[d][3i+k] = x1_pre[i, d+k-1]
          Xb[(long)d * 3072 + 3 * li + 1] = vb;
          if (d <= 510) Xb[(long)(d + 1) * 3072 + 3 * li] = vb;
          else          Xb[(long)511 * 3072 + 3 * li + 2] = __float2bfloat16(0.f);
          if (d >= 1)   Xb[(long)(d - 1) * 3072 + 3 * li + 2] = vb;
          else          Xb[3 * li] = __float2bfloat16(0.f);
        } else if (EPI == 1) {
          v += bias[n];
          outf[(long)m * N + n] = silu_f(v);
        } else if (EPI == 2) {
          v += bias[m];
          (outb + (long)z * sOz)[(long)m * N + n] = __float2bfloat16(silu_f(v));
        } else if (EPI == 3) {
          outf[(long)m * N + n] = v;
        } else {
          v += bias[n];
          outf[(long)m * N + n] = v;
        }
      }
    }
  }
}

// ---------------- delta = softplus(dbc[:, :32] @ W_dt^T + b_dt) ----------------
__global__ __launch_bounds__(256) void delta_kernel(const float* __restrict__ dbc,
                                                    const float* __restrict__ W_dt,
                                                    const float* __restrict__ b_dt,
                                                    float* __restrict__ delta) {
  __shared__ float sd[16][32];
  const int tid = threadIdx.x;
  const int dloc = blockIdx.x * 256 + tid;  // d in [0,512)
  const int m0 = blockIdx.y * 16;
  for (int i = tid; i < 16 * 32; i += 256)
    sd[i >> 5][i & 31] = dbc[(long)(m0 + (i >> 5)) * 64 + (i & 31)];
  __syncthreads();
  float wdt[32];
#pragma unroll
  for (int r = 0; r < 32; r += 4) {
    float4 v = *reinterpret_cast<const float4*>(&W_dt[(long)dloc * 32 + r]);
    wdt[r] = v.x; wdt[r + 1] = v.y; wdt[r + 2] = v.z; wdt[r + 3] = v.w;
  }
  const float bd = b_dt[dloc];
  for (int mi = 0; mi < 16; ++mi) {
    float a = bd;
#pragma unroll
    for (int r = 0; r < 32; ++r) a = fmaf(sd[mi][r], wdt[r], a);
    float sp = fmaxf(a, 0.f) + log1pf(__expf(-fabsf(a)));  // stable softplus
    delta[(long)(m0 + mi) * 512 + dloc] = sp;
  }
}

// ---------------- selective scan + output gate fusion ----------------
// block: 256 threads = 16 n-lanes x 16 d;  grid: (D/16, B)
__global__ __launch_bounds__(256) void scan_kernel(const float* __restrict__ delta,
                                                   const bf16* __restrict__ u_bf,
                                                   const float* __restrict__ dbc,
                                                   const float* __restrict__ A_log,
                                                   const float* __restrict__ Dp,
                                                   const float* __restrict__ x2s,
                                                   const float* __restrict__ x,
                                                   bf16* __restrict__ zb) {
  const int tid = threadIdx.x;
  const int n = tid & 15, dli = tid >> 4;
  const int d = blockIdx.x * 16 + dli;
  const int b = blockIdx.y;
  const float Adn = -__expf(A_log[d * 16 + n]);
  const float Dpv = Dp[d];
  float h = 0.f;
  const long base = (long)b * 1024;
  const float* dl_p = delta + base * 512 + d;
  const bf16* u_p = u_bf + base * 512 + d;
  const float* B_p = dbc + base * 64 + 32 + n;
  const float* C_p = dbc + base * 64 + 48 + n;
  const float* x2_p = x2s + base * 512 + d;
  const float* x_p = x + base * 512 + d;
  bf16* z_p = zb + base * 512 + d;

#pragma unroll 2
  for (int t = 0; t < 1024; ++t) {
    float dv = dl_p[(long)t * 512];
    float uv = __bfloat162float(u_p[(long)t * 512]);
    float Bv = B_p[(long)t * 64];
    float Cv = C_p[(long)t * 64];
    float dA = __expf(dv * Adn);
    h = fmaf(dA, h, dv * uv * Bv);
    float p = h * Cv;
    p += __shfl_xor(p, 1);
    p += __shfl_xor(p, 2);
    p += __shfl_xor(p, 4);
    p += __shfl_xor(p, 8);
    if (n == 0) {
      float y = p + uv * Dpv;
      float zv = y * silu_f(x2_p[(long)t * 512]) + x_p[(long)t * 512];
      z_p[(long)t * 512] = __float2bfloat16(zv);
    }
  }
}

extern "C" void kernel_launch(void* const* d_in, const int* in_sizes, int n_in,
                              void* d_out, int out_size, void* d_ws, size_t ws_size,
                              hipStream_t stream) {
  (void)in_sizes; (void)n_in; (void)out_size; (void)ws_size;
  const float* x    = (const float*)d_in[0];
  const float* W1   = (const float*)d_in[1];
  const float* b1   = (const float*)d_in[2];
  const float* W2   = (const float*)d_in[3];
  const float* b2   = (const float*)d_in[4];
  const float* Wout = (const float*)d_in[5];
  const float* bout = (const float*)d_in[6];
  const float* convw = (const float*)d_in[7];
  const float* convb = (const float*)d_in[8];
  const float* Wdbc = (const float*)d_in[9];
  const float* Wdt  = (const float*)d_in[10];
  const float* bdt  = (const float*)d_in[11];
  const float* Alog = (const float*)d_in[12];
  const float* Dp   = (const float*)d_in[13];
  float* out = (float*)d_out;

  char* ws = (char*)d_ws;
  size_t off = 0;
  auto alloc = [&](size_t bytes) { void* p = ws + off; off += (bytes + 255) & ~(size_t)255; return p; };
  bf16* xb    = (bf16*)alloc(8192L * 512 * 2);
  bf16* w1b   = (bf16*)alloc(512L * 512 * 2);
  bf16* w2b   = (bf16*)alloc(512L * 512 * 2);
  bf16* woutb = (bf16*)alloc(512L * 512 * 2);
  bf16* wdbcb = (bf16*)alloc(64L * 512 * 2);
  bf16* cwb   = (bf16*)alloc(1024L * 3072 * 2);
  bf16* X3t   = (bf16*)alloc(8L * 512 * 3072 * 2);  // 25.2 MB, reused as delta later
  float* x2s  = (float*)alloc(8192L * 512 * 4);
  bf16* x1s   = (bf16*)alloc(8192L * 512 * 2);
  float* dbc  = (float*)alloc(8192L * 64 * 4);
  float* delta = (float*)X3t;  // X3t dead after conv GEMM
  bf16* zb = xb;               // xb dead after GEMM1/GEMM2

  // converts
  f2b_kernel<<<8192 * 512 / 1024, 256, 0, stream>>>(x, xb, 8192 * 512);
  f2b_kernel<<<512 * 512 / 1024, 256, 0, stream>>>(W1, w1b, 512 * 512);
  f2b_kernel<<<512 * 512 / 1024, 256, 0, stream>>>(W2, w2b, 512 * 512);
  f2b_kernel<<<512 * 512 / 1024, 256, 0, stream>>>(Wout, woutb, 512 * 512);
  f2b_kernel<<<64 * 512 / 1024, 256, 0, stream>>>(Wdbc, wdbcb, 64 * 512);
  f2b_kernel<<<1024 * 3072 / 1024, 256, 0, stream>>>(convw, cwb, 1024 * 3072);

  // G1: x@W1^T + b1 -> X3t (shifted triple, bf16)
  gemm_nt<0, 128><<<dim3(64, 4, 1), 256, 0, stream>>>(xb, w1b, b1, nullptr, X3t,
                                                      8192, 512, 512, 0, 0, 0);
  // G2: x@W2^T + b2 -> x2s f32 (RAW — silu applied exactly once, in the scan)
  gemm_nt<4, 128><<<dim3(64, 4, 1), 256, 0, stream>>>(xb, w2b, b2, x2s, nullptr,
                                                      8192, 512, 512, 0, 0, 0);
  // G3 (conv): per batch, silu(cw @ X3t[b]^T + conv_b[o]) -> x1s bf16
  gemm_nt<2, 128><<<dim3(8, 4, 8), 256, 0, stream>>>(cwb, X3t, convb, nullptr, x1s,
                                                     1024, 512, 3072,
                                                     0, 512L * 3072, 1024L * 512);
  // G4: dbc = x1s @ Wdbc^T -> f32 (8192 x 64)
  gemm_nt<3, 64><<<dim3(64, 1, 1), 256, 0, stream>>>(x1s, wdbcb, nullptr, dbc, nullptr,
                                                     8192, 64, 512, 0, 0, 0);
  // delta
  delta_kernel<<<dim3(2, 512, 1), 256, 0, stream>>>(dbc, Wdt, bdt, delta);
  // scan + gate fusion -> zb bf16
  scan_kernel<<<dim3(32, 8, 1), 256, 0, stream>>>(delta, x1s, dbc, Alog, Dp, x2s, x, zb);
  // G5: out = zb @ Wout^T + bout -> f32
  gemm_nt<4, 128><<<dim3(64, 4, 1), 256, 0, stream>>>(zb, woutb, bout, out, nullptr,
                                                      8192, 512, 512, 0, 0, 0);
}

// Round 3
// 259.905 us; speedup vs baseline: 3.5228x; 3.5228x over previous
//
#include <hip/hip_runtime.h>
#include <hip/hip_bf16.h>

typedef __hip_bfloat16 bf16;
typedef __bf16 bf16x8 __attribute__((ext_vector_type(8)));
typedef float f32x4 __attribute__((ext_vector_type(4)));

static_assert(sizeof(bf16) == 2, "bf16 must be 2 bytes");

#define NC 32   // chunks over L=1024
#define CH 32   // steps per chunk

__device__ __forceinline__ float silu_f(float v) { return v / (1.0f + __expf(-v)); }

__device__ __forceinline__ void gload16(const bf16* g, bf16* l) {
  __builtin_amdgcn_global_load_lds((const __attribute__((address_space(1))) void*)g,
                                   (__attribute__((address_space(3))) void*)l,
                                   16, 0, 0);
}

// ---------------- f32 -> bf16 convert ----------------
__global__ __launch_bounds__(256) void f2b_kernel(const float* __restrict__ in,
                                                  bf16* __restrict__ out, int n) {
  int i = (blockIdx.x * 256 + threadIdx.x) * 4;
  if (i + 3 < n) {
    float4 v = *reinterpret_cast<const float4*>(in + i);
    bf16 a = __float2bfloat16(v.x), b = __float2bfloat16(v.y),
         c = __float2bfloat16(v.z), d = __float2bfloat16(v.w);
    ushort4 s;
    s.x = __builtin_bit_cast(unsigned short, a);
    s.y = __builtin_bit_cast(unsigned short, b);
    s.z = __builtin_bit_cast(unsigned short, c);
    s.w = __builtin_bit_cast(unsigned short, d);
    *reinterpret_cast<ushort4*>(out + i) = s;
  }
}

// ---------------- MFMA GEMM, C[M,N] = A[M,K] * B[N,K]^T ----------------
// EPI: 0 = +bias[n], write X3t shifted-triple bf16 (conv operand build)
//      2 = +bias[m], silu, bf16 out (+batch offset via sOz)
//      3 = plain f32 out
//      4 = +bias[n], f32 out
template <int EPI, int BN>
__global__ __launch_bounds__(256) void gemm_nt(const bf16* __restrict__ A,
                                               const bf16* __restrict__ Bw,
                                               const float* __restrict__ bias,
                                               float* __restrict__ outf,
                                               bf16* __restrict__ outb,
                                               int M, int N, int K,
                                               long sAz, long sBz, long sOz) {
  constexpr int BM = 128, BK = 64;
  constexpr int WNF = BN / 32;
  __shared__ __align__(16) bf16 As[BM * BK];
  __shared__ __align__(16) bf16 Bs[BN * BK];

  const int tid = threadIdx.x;
  const int w = tid >> 6, l = tid & 63;
  const int wm = w >> 1, wn = w & 1;
  const int m0 = blockIdx.x * BM, n0 = blockIdx.y * BN;
  const int z = blockIdx.z;
  const bf16* Ab = A + (long)z * sAz + (long)m0 * K;
  const bf16* Bb = Bw + (long)z * sBz + (long)n0 * K;

  f32x4 acc[4][WNF];
#pragma unroll
  for (int i = 0; i < 4; ++i)
#pragma unroll
    for (int j = 0; j < WNF; ++j) acc[i][j] = (f32x4){0.f, 0.f, 0.f, 0.f};

  constexpr int APW = (BM * BK / 512) / 4;
  constexpr int BPW = (BN * BK / 512) / 4;

  for (int k0 = 0; k0 < K; k0 += BK) {
#pragma unroll
    for (int j = 0; j < APW; ++j) {
      int iss = w * APW + j;
      int e = iss * 512 + l * 8;
      gload16(Ab + (long)(e >> 6) * K + k0 + (e & 63), &As[iss * 512]);
    }
#pragma unroll
    for (int j = 0; j < BPW; ++j) {
      int iss = w * BPW + j;
      int e = iss * 512 + l * 8;
      gload16(Bb + (long)(e >> 6) * K + k0 + (e & 63), &Bs[iss * 512]);
    }
    __syncthreads();
    const int lr = l & 15;
#pragma unroll
    for (int kk = 0; kk < BK; kk += 32) {
      const int lk = (l >> 4) * 8 + kk;
      bf16x8 af[4], bfg[WNF];
#pragma unroll
      for (int mi = 0; mi < 4; ++mi)
        af[mi] = *reinterpret_cast<const bf16x8*>(&As[(wm * 64 + mi * 16 + lr) * BK + lk]);
#pragma unroll
      for (int ni = 0; ni < WNF; ++ni)
        bfg[ni] = *reinterpret_cast<const bf16x8*>(&Bs[(wn * (BN / 2) + ni * 16 + lr) * BK + lk]);
#pragma unroll
      for (int mi = 0; mi < 4; ++mi)
#pragma unroll
        for (int ni = 0; ni < WNF; ++ni)
          acc[mi][ni] = __builtin_amdgcn_mfma_f32_16x16x32_bf16(af[mi], bfg[ni], acc[mi][ni], 0, 0, 0);
    }
    __syncthreads();
  }

  const int lr = l & 15, lq = l >> 4;
#pragma unroll
  for (int mi = 0; mi < 4; ++mi) {
#pragma unroll
    for (int ni = 0; ni < WNF; ++ni) {
#pragma unroll
      for (int j = 0; j < 4; ++j) {
        int m = m0 + wm * 64 + mi * 16 + lq * 4 + j;
        int n = n0 + wn * (BN / 2) + ni * 16 + lr;
        float v = acc[mi][ni][j];
        if (EPI == 0) {
          v += bias[n];
          bf16 vb = __float2bfloat16(v);
          bf16* Xb = outb + (long)(m >> 10) * (512L * 3072);
          int li = m & 1023;
          int d = n;
          Xb[(long)d * 3072 + 3 * li + 1] = vb;
          if (d <= 510) Xb[(long)(d + 1) * 3072 + 3 * li] = vb;
          else          Xb[(long)511 * 3072 + 3 * li + 2] = __float2bfloat16(0.f);
          if (d >= 1)   Xb[(long)(d - 1) * 3072 + 3 * li + 2] = vb;
          else          Xb[3 * li] = __float2bfloat16(0.f);
        } else if (EPI == 2) {
          v += bias[m];
          (outb + (long)z * sOz)[(long)m * N + n] = __float2bfloat16(silu_f(v));
        } else if (EPI == 3) {
          outf[(long)m * N + n] = v;
        } else {
          v += bias[n];
          outf[(long)m * N + n] = v;
        }
      }
    }
  }
}

// ---------------- delta = softplus(dbc[:, :32] @ W_dt^T + b_dt) ----------------
__global__ __launch_bounds__(256) void delta_kernel(const float* __restrict__ dbc,
                                                    const float* __restrict__ W_dt,
                                                    const float* __restrict__ b_dt,
                                                    float* __restrict__ delta) {
  __shared__ float sd[16][32];
  const int tid = threadIdx.x;
  const int dloc = blockIdx.x * 256 + tid;
  const int m0 = blockIdx.y * 16;
  for (int i = tid; i < 16 * 32; i += 256)
    sd[i >> 5][i & 31] = dbc[(long)(m0 + (i >> 5)) * 64 + (i & 31)];
  __syncthreads();
  float wdt[32];
#pragma unroll
  for (int r = 0; r < 32; r += 4) {
    float4 v = *reinterpret_cast<const float4*>(&W_dt[(long)dloc * 32 + r]);
    wdt[r] = v.x; wdt[r + 1] = v.y; wdt[r + 2] = v.z; wdt[r + 3] = v.w;
  }
  const float bd = b_dt[dloc];
  for (int mi = 0; mi < 16; ++mi) {
    float a = bd;
#pragma unroll
    for (int r = 0; r < 32; ++r) a = fmaf(sd[mi][r], wdt[r], a);
    float sp = fmaxf(a, 0.f) + log1pf(__expf(-fabsf(a)));
    delta[(long)(m0 + mi) * 512 + dloc] = sp;
  }
}

// ---------------- chunked selective scan ----------------
// Phase 1: per chunk, P = prod(dA), Q = local scan from h=0.
// grid (D/256, NC, B), block 256; thread owns one d, all 16 n.
__global__ __launch_bounds__(256) void scan_p1(const float* __restrict__ delta,
                                               const bf16* __restrict__ u_bf,
                                               const float* __restrict__ dbc,
                                               const float* __restrict__ A_log,
                                               float* __restrict__ P,
                                               float* __restrict__ Q) {
  const int tid = threadIdx.x;
  const int d = blockIdx.x * 256 + tid;
  const int c = blockIdx.y, b = blockIdx.z;
  __shared__ float sB[CH][16];
  for (int i = tid; i < CH * 16; i += 256) {
    int tt = i >> 4, j = i & 15;
    sB[tt][j] = dbc[((long)b * 1024 + c * CH + tt) * 64 + 32 + j];
  }
  __syncthreads();
  float Adn[16];
#pragma unroll
  for (int n = 0; n < 16; ++n) Adn[n] = -__expf(A_log[d * 16 + n]);
  float p[16], q[16];
#pragma unroll
  for (int n = 0; n < 16; ++n) { p[n] = 1.f; q[n] = 0.f; }
  const long rowb = (long)b * 1024 + c * CH;
#pragma unroll 2
  for (int tt = 0; tt < CH; ++tt) {
    long off = (rowb + tt) * 512 + d;
    float dv = delta[off];
    float uv = __bfloat162float(u_bf[off]);
    float s = dv * uv;
#pragma unroll
    for (int n = 0; n < 16; ++n) {
      float dA = __expf(dv * Adn[n]);
      p[n] *= dA;
      q[n] = fmaf(dA, q[n], s * sB[tt][n]);
    }
  }
  float* Pp = P + (((long)b * NC + c) * 512 + d) * 16;
  float* Qp = Q + (((long)b * NC + c) * 512 + d) * 16;
#pragma unroll
  for (int n4 = 0; n4 < 4; ++n4) {
    *reinterpret_cast<float4*>(Pp + n4 * 4) = make_float4(p[n4*4], p[n4*4+1], p[n4*4+2], p[n4*4+3]);
    *reinterpret_cast<float4*>(Qp + n4 * 4) = make_float4(q[n4*4], q[n4*4+1], q[n4*4+2], q[n4*4+3]);
  }
}

// Phase 2: scan over chunk summaries. grid (8192/256, B), block 256.
__global__ __launch_bounds__(256) void scan_p2(const float* __restrict__ P,
                                               const float* __restrict__ Q,
                                               float* __restrict__ Hin) {
  const int dn = blockIdx.x * 256 + threadIdx.x;
  const int b = blockIdx.y;
  float h = 0.f;
#pragma unroll 4
  for (int c = 0; c < NC; ++c) {
    long idx = ((long)b * NC + c) * 8192 + dn;
    Hin[idx] = h;
    h = fmaf(P[idx], h, Q[idx]);
  }
}

// Phase 3: re-scan chunk from Hin, emit z = y*silu(x2)+x (bf16).
__global__ __launch_bounds__(256) void scan_p3(const float* __restrict__ delta,
                                               const bf16* __restrict__ u_bf,
                                               const float* __restrict__ dbc,
                                               const float* __restrict__ A_log,
                                               const float* __restrict__ Dp,
                                               const float* __restrict__ x2s,
                                               const float* __restrict__ x,
                                               const float* __restrict__ Hin,
                                               bf16* __restrict__ zb) {
  const int tid = threadIdx.x;
  const int d = blockIdx.x * 256 + tid;
  const int c = blockIdx.y, b = blockIdx.z;
  __shared__ float sB[CH][16], sC[CH][16];
  for (int i = tid; i < CH * 32; i += 256) {
    int tt = i >> 5, j = i & 31;
    float v = dbc[((long)b * 1024 + c * CH + tt) * 64 + 32 + j];
    if (j < 16) sB[tt][j] = v;
    else        sC[tt][j - 16] = v;
  }
  __syncthreads();
  float Adn[16];
#pragma unroll
  for (int n = 0; n < 16; ++n) Adn[n] = -__expf(A_log[d * 16 + n]);
  float h[16];
  const float* Hp = Hin + ((long)b * NC + c) * 8192 + (long)d * 16;
#pragma unroll
  for (int n4 = 0; n4 < 4; ++n4) {
    float4 v = *reinterpret_cast<const float4*>(Hp + n4 * 4);
    h[n4*4] = v.x; h[n4*4+1] = v.y; h[n4*4+2] = v.z; h[n4*4+3] = v.w;
  }
  const float Dpv = Dp[d];
  const long rowb = (long)b * 1024 + c * CH;
#pragma unroll 2
  for (int tt = 0; tt < CH; ++tt) {
    long off = (rowb + tt) * 512 + d;
    float dv = delta[off];
    float uv = __bfloat162float(u_bf[off]);
    float s = dv * uv;
    float y = uv * Dpv;
#pragma unroll
    for (int n = 0; n < 16; ++n) {
      float dA = __expf(dv * Adn[n]);
      h[n] = fmaf(dA, h[n], s * sB[tt][n]);
      y = fmaf(h[n], sC[tt][n], y);
    }
    float zv = fmaf(y, silu_f(x2s[off]), x[off]);
    zb[off] = __float2bfloat16(zv);
  }
}

extern "C" void kernel_launch(void* const* d_in, const int* in_sizes, int n_in,
                              void* d_out, int out_size, void* d_ws, size_t ws_size,
                              hipStream_t stream) {
  (void)in_sizes; (void)n_in; (void)out_size; (void)ws_size;
  const float* x    = (const float*)d_in[0];
  const float* W1   = (const float*)d_in[1];
  const float* b1   = (const float*)d_in[2];
  const float* W2   = (const float*)d_in[3];
  const float* b2   = (const float*)d_in[4];
  const float* Wout = (const float*)d_in[5];
  const float* bout = (const float*)d_in[6];
  const float* convw = (const float*)d_in[7];
  const float* convb = (const float*)d_in[8];
  const float* Wdbc = (const float*)d_in[9];
  const float* Wdt  = (const float*)d_in[10];
  const float* bdt  = (const float*)d_in[11];
  const float* Alog = (const float*)d_in[12];
  const float* Dp   = (const float*)d_in[13];
  float* out = (float*)d_out;

  char* ws = (char*)d_ws;
  size_t off = 0;
  auto alloc = [&](size_t bytes) { void* p = ws + off; off += (bytes + 255) & ~(size_t)255; return p; };
  bf16* xb    = (bf16*)alloc(8192L * 512 * 2);
  bf16* w1b   = (bf16*)alloc(512L * 512 * 2);
  bf16* w2b   = (bf16*)alloc(512L * 512 * 2);
  bf16* woutb = (bf16*)alloc(512L * 512 * 2);
  bf16* wdbcb = (bf16*)alloc(64L * 512 * 2);
  bf16* cwb   = (bf16*)alloc(1024L * 3072 * 2);
  bf16* X3t   = (bf16*)alloc(8L * 512 * 3072 * 2);  // 25.2 MB; head->delta, tail->P after G3
  float* x2s  = (float*)alloc(8192L * 512 * 4);
  bf16* x1s   = (bf16*)alloc(8192L * 512 * 2);
  float* dbc  = (float*)alloc(8192L * 64 * 4);
  float* Q    = (float*)alloc(8L * NC * 8192 * 4);
  float* Hin  = (float*)alloc(8L * NC * 8192 * 4);
  float* delta = (float*)X3t;                          // 16.78 MB
  float* P     = (float*)((char*)X3t + 8192L * 512 * 4);  // 8.39 MB (fits X3t tail exactly)
  bf16* zb = xb;  // xb dead after G1/G2

  // converts
  f2b_kernel<<<8192 * 512 / 1024, 256, 0, stream>>>(x, xb, 8192 * 512);
  f2b_kernel<<<512 * 512 / 1024, 256, 0, stream>>>(W1, w1b, 512 * 512);
  f2b_kernel<<<512 * 512 / 1024, 256, 0, stream>>>(W2, w2b, 512 * 512);
  f2b_kernel<<<512 * 512 / 1024, 256, 0, stream>>>(Wout, woutb, 512 * 512);
  f2b_kernel<<<64 * 512 / 1024, 256, 0, stream>>>(Wdbc, wdbcb, 64 * 512);
  f2b_kernel<<<1024 * 3072 / 1024, 256, 0, stream>>>(convw, cwb, 1024 * 3072);

  // G1: x@W1^T + b1 -> X3t (shifted triple, bf16)
  gemm_nt<0, 128><<<dim3(64, 4, 1), 256, 0, stream>>>(xb, w1b, b1, nullptr, X3t,
                                                      8192, 512, 512, 0, 0, 0);
  // G2: x@W2^T + b2 -> x2s f32 (raw; silu applied once, in scan_p3)
  gemm_nt<4, 128><<<dim3(64, 4, 1), 256, 0, stream>>>(xb, w2b, b2, x2s, nullptr,
                                                      8192, 512, 512, 0, 0, 0);
  // G3 (conv): per batch, silu(cw @ X3t[b]^T + conv_b[o]) -> x1s bf16
  gemm_nt<2, 128><<<dim3(8, 4, 8), 256, 0, stream>>>(cwb, X3t, convb, nullptr, x1s,
                                                     1024, 512, 3072,
                                                     0, 512L * 3072, 1024L * 512);
  // G4: dbc = x1s @ Wdbc^T -> f32 (8192 x 64)
  gemm_nt<3, 64><<<dim3(64, 1, 1), 256, 0, stream>>>(x1s, wdbcb, nullptr, dbc, nullptr,
                                                     8192, 64, 512, 0, 0, 0);
  // delta (writes into X3t head — X3t dead after G3)
  delta_kernel<<<dim3(2, 512, 1), 256, 0, stream>>>(dbc, Wdt, bdt, delta);
  // chunked scan
  scan_p1<<<dim3(2, NC, 8), 256, 0, stream>>>(delta, x1s, dbc, Alog, P, Q);
  scan_p2<<<dim3(32, 8, 1), 256, 0, stream>>>(P, Q, Hin);
  scan_p3<<<dim3(2, NC, 8), 256, 0, stream>>>(delta, x1s, dbc, Alog, Dp, x2s, x, Hin, zb);
  // G5: out = zb @ Wout^T + bout -> f32
  gemm_nt<4, 128><<<dim3(64, 4, 1), 256, 0, stream>>>(zb, woutb, bout, out, nullptr,
                                                      8192, 512, 512, 0, 0, 0);
}

// Round 4
// 186.728 us; speedup vs baseline: 4.9033x; 1.3919x over previous
//
#include <hip/hip_runtime.h>
#include <hip/hip_bf16.h>

typedef __hip_bfloat16 bf16;
typedef __bf16 bf16x8 __attribute__((ext_vector_type(8)));
typedef float f32x4 __attribute__((ext_vector_type(4)));

static_assert(sizeof(bf16) == 2, "bf16 must be 2 bytes");

#define NC 32   // chunks over L=1024
#define CH 32   // steps per chunk
#define X1TP_BSTRIDE (514L * 1024)  // padded x1^T per batch: rows -1..512

__device__ __forceinline__ float silu_f(float v) { return v / (1.0f + __expf(-v)); }

__device__ __forceinline__ void gload16(const bf16* g, bf16* l) {
  __builtin_amdgcn_global_load_lds((const __attribute__((address_space(1))) void*)g,
                                   (__attribute__((address_space(3))) void*)l,
                                   16, 0, 0);
}

// ---------------- f32 -> bf16 convert ----------------
__global__ __launch_bounds__(256) void f2b_kernel(const float* __restrict__ in,
                                                  bf16* __restrict__ out, int n) {
  int i = (blockIdx.x * 256 + threadIdx.x) * 4;
  if (i + 3 < n) {
    float4 v = *reinterpret_cast<const float4*>(in + i);
    ushort4 s;
    s.x = __builtin_bit_cast(unsigned short, __float2bfloat16(v.x));
    s.y = __builtin_bit_cast(unsigned short, __float2bfloat16(v.y));
    s.z = __builtin_bit_cast(unsigned short, __float2bfloat16(v.z));
    s.w = __builtin_bit_cast(unsigned short, __float2bfloat16(v.w));
    *reinterpret_cast<ushort4*>(out + i) = s;
  }
}

// conv_w (1024x1024x3 f32, tap-minor) -> cw_split bf16 [o][k*1024 + i]
__global__ __launch_bounds__(256) void csplit_kernel(const float* __restrict__ cw,
                                                     bf16* __restrict__ cws) {
  long idx = (long)blockIdx.x * 256 + threadIdx.x;  // o*1024 + i
  int o = (int)(idx >> 10), i = (int)(idx & 1023);
  float a = cw[idx * 3], b = cw[idx * 3 + 1], c = cw[idx * 3 + 2];
  cws[(long)o * 3072 + i]        = __float2bfloat16(a);
  cws[(long)o * 3072 + 1024 + i] = __float2bfloat16(b);
  cws[(long)o * 3072 + 2048 + i] = __float2bfloat16(c);
}

// zero the pad rows (d=-1 and d=512) of x1tp for all batches
__global__ __launch_bounds__(256) void zpad_kernel(bf16* __restrict__ x1tp) {
  int e = blockIdx.x * 256 + threadIdx.x;  // 8*2*1024 = 16384
  int b = e >> 11, rem = e & 2047;
  int r = rem >> 10, i = rem & 1023;
  x1tp[(long)b * X1TP_BSTRIDE + (long)r * (513 * 1024) + i] = __float2bfloat16(0.f);
}

// ---------------- MFMA GEMM, C[M,N] = A[M,K] * B[N,K]^T ----------------
// 2-phase prefetch (dbuf LDS, stage t+1 after barrier, 1 barrier/iter) + T2 swizzle.
// EPI: 2 = +bias[m], silu, bf16 -> outb + z*sOz, row-major [m][n]
//      3 = plain f32 out
//      4 = +bias[n], f32 out
//      5 = +bias[m], bf16 -> x1tp padded-transposed layout (G1t)
// CONVB: B is virtual conv operand: row n, col kb*1024+i -> x1tp[z][(n+kb)*1024 + i]
template <int EPI, int BM, int BN, int CONVB>
__global__ __launch_bounds__(256) void gemm_nt(const bf16* __restrict__ A,
                                               const bf16* __restrict__ Bw,
                                               const float* __restrict__ bias,
                                               float* __restrict__ outf,
                                               bf16* __restrict__ outb,
                                               int M, int N, int K,
                                               long sAz, long sBz, long sOz) {
  constexpr int BK = 64;
  constexpr int MI = BM / 32;   // 16-row frags per wave along M
  constexpr int WNF = BN / 32;  // 16-col frags per wave along N
  constexpr int APW = BM / 32;  // A stage issues per wave
  constexpr int BPW = BN / 32;  // B stage issues per wave
  __shared__ __align__(16) bf16 As[2][BM * BK];
  __shared__ __align__(16) bf16 Bs[2][BN * BK];

  const int tid = threadIdx.x;
  const int w = tid >> 6, l = tid & 63;
  const int wm = w >> 1, wn = w & 1;
  const int m0 = blockIdx.x * BM, n0 = blockIdx.y * BN;
  const int z = blockIdx.z;
  const bf16* Ab = A + (long)z * sAz + (long)m0 * K;
  const bf16* Bb = Bw + (long)z * sBz;

  const int lrow = l >> 3;                              // row within 8-row stage group
  const int lcol = (((l & 7) ^ (l >> 3)) << 3);         // swizzled source col (elements)

  auto stage = [&](int buf, int k0) {
#pragma unroll
    for (int j = 0; j < APW; ++j) {
      int iss = w * APW + j;
      int row = iss * 8 + lrow;
      gload16(Ab + (long)row * K + k0 + lcol, &As[buf][iss * 512]);
    }
#pragma unroll
    for (int j = 0; j < BPW; ++j) {
      int iss = w * BPW + j;
      int row = iss * 8 + lrow;
      const bf16* src;
      if (CONVB) src = Bb + (long)(n0 + row + (k0 >> 10)) * 1024 + (k0 & 1023) + lcol;
      else       src = Bb + (long)(n0 + row) * K + k0 + lcol;
      gload16(src, &Bs[buf][iss * 512]);
    }
  };

  f32x4 acc[MI][WNF] = {};
  const int nt = K / BK;
  const int lr = l & 15;
  const int lko = (l >> 4) * 8;
  const int xorm = (lr & 7) << 3;

  stage(0, 0);
  for (int t = 0; t < nt; ++t) {
    const int cur = t & 1;
    asm volatile("s_waitcnt vmcnt(0)" ::: "memory");
    __syncthreads();
    if (t + 1 < nt) stage(cur ^ 1, (t + 1) * BK);
#pragma unroll
    for (int kk = 0; kk < 2; ++kk) {
      const int col = (lko + kk * 32) ^ xorm;
      bf16x8 af[MI], bfg[WNF];
#pragma unroll
      for (int mi = 0; mi < MI; ++mi)
        af[mi] = *reinterpret_cast<const bf16x8*>(&As[cur][(wm * (BM / 2) + mi * 16 + lr) * 64 + col]);
#pragma unroll
      for (int ni = 0; ni < WNF; ++ni)
        bfg[ni] = *reinterpret_cast<const bf16x8*>(&Bs[cur][(wn * (BN / 2) + ni * 16 + lr) * 64 + col]);
#pragma unroll
      for (int mi = 0; mi < MI; ++mi)
#pragma unroll
        for (int ni = 0; ni < WNF; ++ni)
          acc[mi][ni] = __builtin_amdgcn_mfma_f32_16x16x32_bf16(af[mi], bfg[ni], acc[mi][ni], 0, 0, 0);
    }
  }

  // epilogue: D mapping col = lane&15, row = (lane>>4)*4 + j
  const int lq = l >> 4;
#pragma unroll
  for (int mi = 0; mi < MI; ++mi) {
#pragma unroll
    for (int ni = 0; ni < WNF; ++ni) {
#pragma unroll
      for (int j = 0; j < 4; ++j) {
        int m = m0 + wm * (BM / 2) + mi * 16 + lq * 4 + j;
        int n = n0 + wn * (BN / 2) + ni * 16 + lr;
        float v = acc[mi][ni][j];
        if (EPI == 2) {
          v += bias[m];
          (outb + (long)z * sOz)[(long)m * N + n] = __float2bfloat16(silu_f(v));
        } else if (EPI == 3) {
          outf[(long)m * N + n] = v;
        } else if (EPI == 4) {
          v += bias[n];
          outf[(long)m * N + n] = v;
        } else {  // EPI 5: x1tp padded transposed
          v += bias[m];
          int b = n >> 10, li = n & 1023;
          outb[(long)b * X1TP_BSTRIDE + (long)(m + 1) * 1024 + li] = __float2bfloat16(v);
        }
      }
    }
  }
}

// ---------------- chunked selective scan (delta fused) ----------------
// Phase 1: per chunk, P = prod(dA), Q = local scan from h=0.
__global__ __launch_bounds__(256) void scan_p1(const bf16* __restrict__ u_bf,
                                               const float* __restrict__ dbc,
                                               const float* __restrict__ W_dt,
                                               const float* __restrict__ b_dt,
                                               const float* __restrict__ A_log,
                                               float* __restrict__ P,
                                               float* __restrict__ Q) {
  const int tid = threadIdx.x;
  const int d = blockIdx.x * 256 + tid;
  const int c = blockIdx.y, b = blockIdx.z;
  __shared__ float sD[CH][64];
  for (int i = tid; i < CH * 64; i += 256) {
    int tt = i >> 6, j = i & 63;
    sD[tt][j] = dbc[((long)b * 1024 + c * CH + tt) * 64 + j];
  }
  __syncthreads();
  float wdt[32];
#pragma unroll
  for (int r = 0; r < 32; r += 4) {
    float4 v = *reinterpret_cast<const float4*>(&W_dt[(long)d * 32 + r]);
    wdt[r] = v.x; wdt[r + 1] = v.y; wdt[r + 2] = v.z; wdt[r + 3] = v.w;
  }
  const float bd = b_dt[d];
  float Adn[16];
#pragma unroll
  for (int n = 0; n < 16; ++n) Adn[n] = -__expf(A_log[d * 16 + n]);
  float p[16], q[16];
#pragma unroll
  for (int n = 0; n < 16; ++n) { p[n] = 1.f; q[n] = 0.f; }
  const long rowb = (long)b * 1024 + c * CH;
  for (int tt = 0; tt < CH; ++tt) {
    float a = bd;
#pragma unroll
    for (int r = 0; r < 32; ++r) a = fmaf(sD[tt][r], wdt[r], a);
    float dv = fmaxf(a, 0.f) + log1pf(__expf(-fabsf(a)));  // softplus
    float uv = __bfloat162float(u_bf[(rowb + tt) * 512 + d]);
    float s = dv * uv;
#pragma unroll
    for (int n = 0; n < 16; ++n) {
      float dA = __expf(dv * Adn[n]);
      p[n] *= dA;
      q[n] = fmaf(dA, q[n], s * sD[tt][32 + n]);
    }
  }
  float* Pp = P + ((long)b * NC + c) * 8192 + (long)d * 16;
  float* Qp = Q + ((long)b * NC + c) * 8192 + (long)d * 16;
#pragma unroll
  for (int n4 = 0; n4 < 4; ++n4) {
    *reinterpret_cast<float4*>(Pp + n4 * 4) = make_float4(p[n4*4], p[n4*4+1], p[n4*4+2], p[n4*4+3]);
    *reinterpret_cast<float4*>(Qp + n4 * 4) = make_float4(q[n4*4], q[n4*4+1], q[n4*4+2], q[n4*4+3]);
  }
}

// Phase 2: scan over chunk summaries.
__global__ __launch_bounds__(256) void scan_p2(const float* __restrict__ P,
                                               const float* __restrict__ Q,
                                               float* __restrict__ Hin) {
  const int dn = blockIdx.x * 256 + threadIdx.x;
  const int b = blockIdx.y;
  float h = 0.f;
#pragma unroll 4
  for (int c = 0; c < NC; ++c) {
    long idx = ((long)b * NC + c) * 8192 + dn;
    Hin[idx] = h;
    h = fmaf(P[idx], h, Q[idx]);
  }
}

// Phase 3: re-scan chunk from Hin, emit z = y*silu(x2)+x (bf16).
__global__ __launch_bounds__(256) void scan_p3(const bf16* __restrict__ u_bf,
                                               const float* __restrict__ dbc,
                                               const float* __restrict__ W_dt,
                                               const float* __restrict__ b_dt,
                                               const float* __restrict__ A_log,
                                               const float* __restrict__ Dp,
                                               const float* __restrict__ x2s,
                                               const float* __restrict__ x,
                                               const float* __restrict__ Hin,
                                               bf16* __restrict__ zb) {
  const int tid = threadIdx.x;
  const int d = blockIdx.x * 256 + tid;
  const int c = blockIdx.y, b = blockIdx.z;
  __shared__ float sD[CH][64];
  for (int i = tid; i < CH * 64; i += 256) {
    int tt = i >> 6, j = i & 63;
    sD[tt][j] = dbc[((long)b * 1024 + c * CH + tt) * 64 + j];
  }
  __syncthreads();
  float wdt[32];
#pragma unroll
  for (int r = 0; r < 32; r += 4) {
    float4 v = *reinterpret_cast<const float4*>(&W_dt[(long)d * 32 + r]);
    wdt[r] = v.x; wdt[r + 1] = v.y; wdt[r + 2] = v.z; wdt[r + 3] = v.w;
  }
  const float bd = b_dt[d];
  float Adn[16];
#pragma unroll
  for (int n = 0; n < 16; ++n) Adn[n] = -__expf(A_log[d * 16 + n]);
  float h[16];
  const float* Hp = Hin + ((long)b * NC + c) * 8192 + (long)d * 16;
#pragma unroll
  for (int n4 = 0; n4 < 4; ++n4) {
    float4 v = *reinterpret_cast<const float4*>(Hp + n4 * 4);
    h[n4*4] = v.x; h[n4*4+1] = v.y; h[n4*4+2] = v.z; h[n4*4+3] = v.w;
  }
  const float Dpv = Dp[d];
  const long rowb = (long)b * 1024 + c * CH;
  for (int tt = 0; tt < CH; ++tt) {
    long off = (rowb + tt) * 512 + d;
    float a = bd;
#pragma unroll
    for (int r = 0; r < 32; ++r) a = fmaf(sD[tt][r], wdt[r], a);
    float dv = fmaxf(a, 0.f) + log1pf(__expf(-fabsf(a)));
    float uv = __bfloat162float(u_bf[off]);
    float s = dv * uv;
    float y = uv * Dpv;
#pragma unroll
    for (int n = 0; n < 16; ++n) {
      float dA = __expf(dv * Adn[n]);
      h[n] = fmaf(dA, h[n], s * sD[tt][32 + n]);
      y = fmaf(h[n], sD[tt][48 + n], y);
    }
    float zv = fmaf(y, silu_f(x2s[off]), x[off]);
    zb[off] = __float2bfloat16(zv);
  }
}

extern "C" void kernel_launch(void* const* d_in, const int* in_sizes, int n_in,
                              void* d_out, int out_size, void* d_ws, size_t ws_size,
                              hipStream_t stream) {
  (void)in_sizes; (void)n_in; (void)out_size; (void)ws_size;
  const float* x    = (const float*)d_in[0];
  const float* W1   = (const float*)d_in[1];
  const float* b1   = (const float*)d_in[2];
  const float* W2   = (const float*)d_in[3];
  const float* b2   = (const float*)d_in[4];
  const float* Wout = (const float*)d_in[5];
  const float* bout = (const float*)d_in[6];
  const float* convw = (const float*)d_in[7];
  const float* convb = (const float*)d_in[8];
  const float* Wdbc = (const float*)d_in[9];
  const float* Wdt  = (const float*)d_in[10];
  const float* bdt  = (const float*)d_in[11];
  const float* Alog = (const float*)d_in[12];
  const float* Dp   = (const float*)d_in[13];
  float* out = (float*)d_out;

  char* ws = (char*)d_ws;
  size_t off = 0;
  auto alloc = [&](size_t bytes) { void* p = ws + off; off += (bytes + 255) & ~(size_t)255; return p; };
  bf16* xb     = (bf16*)alloc(8192L * 512 * 2);
  bf16* w1b    = (bf16*)alloc(512L * 512 * 2);
  bf16* w2b    = (bf16*)alloc(512L * 512 * 2);
  bf16* woutb  = (bf16*)alloc(512L * 512 * 2);
  bf16* wdbcb  = (bf16*)alloc(64L * 512 * 2);
  bf16* cws    = (bf16*)alloc(1024L * 3072 * 2);
  bf16* x1tp   = (bf16*)alloc(8L * X1TP_BSTRIDE * 2);
  float* x2s   = (float*)alloc(8192L * 512 * 4);
  bf16* x1s    = (bf16*)alloc(8192L * 512 * 2);
  float* dbc   = (float*)alloc(8192L * 64 * 4);
  float* P     = (float*)alloc(8L * NC * 8192 * 4);
  float* Q     = (float*)alloc(8L * NC * 8192 * 4);
  float* Hin   = (float*)alloc(8L * NC * 8192 * 4);
  bf16* zb = xb;  // xb dead after G1t/G2

  // converts
  f2b_kernel<<<8192 * 512 / 1024, 256, 0, stream>>>(x, xb, 8192 * 512);
  f2b_kernel<<<512 * 512 / 1024, 256, 0, stream>>>(W1, w1b, 512 * 512);
  f2b_kernel<<<512 * 512 / 1024, 256, 0, stream>>>(W2, w2b, 512 * 512);
  f2b_kernel<<<512 * 512 / 1024, 256, 0, stream>>>(Wout, woutb, 512 * 512);
  f2b_kernel<<<64 * 512 / 1024, 256, 0, stream>>>(Wdbc, wdbcb, 64 * 512);
  csplit_kernel<<<1024 * 1024 / 256, 256, 0, stream>>>(convw, cws);
  zpad_kernel<<<64, 256, 0, stream>>>(x1tp);

  // G1t: x1^T = W1 @ x^T + b1[m] -> x1tp (padded, bf16)
  gemm_nt<5, 64, 128, 0><<<dim3(8, 64, 1), 256, 0, stream>>>(
      w1b, xb, b1, nullptr, x1tp, 512, 8192, 512, 0, 0, 0);
  // G2: x@W2^T + b2 -> x2s f32
  gemm_nt<4, 64, 128, 0><<<dim3(128, 4, 1), 256, 0, stream>>>(
      xb, w2b, b2, x2s, nullptr, 8192, 512, 512, 0, 0, 0);
  // G3 (conv): silu(cw_split @ Bv^T + conv_b[o]) -> x1s bf16, per batch
  gemm_nt<2, 64, 128, 1><<<dim3(16, 4, 8), 256, 0, stream>>>(
      cws, x1tp, convb, nullptr, x1s, 1024, 512, 3072, 0, X1TP_BSTRIDE, 1024L * 512);
  // G4: dbc = x1s @ Wdbc^T -> f32 (8192 x 64)
  gemm_nt<3, 64, 64, 0><<<dim3(128, 1, 1), 256, 0, stream>>>(
      x1s, wdbcb, nullptr, dbc, nullptr, 8192, 64, 512, 0, 0, 0);
  // chunked scan (delta fused into p1/p3)
  scan_p1<<<dim3(2, NC, 8), 256, 0, stream>>>(x1s, dbc, Wdt, bdt, Alog, P, Q);
  scan_p2<<<dim3(32, 8, 1), 256, 0, stream>>>(P, Q, Hin);
  scan_p3<<<dim3(2, NC, 8), 256, 0, stream>>>(x1s, dbc, Wdt, bdt, Alog, Dp, x2s, x, Hin, zb);
  // G5: out = zb @ Wout^T + bout -> f32
  gemm_nt<4, 64, 128, 0><<<dim3(128, 4, 1), 256, 0, stream>>>(
      zb, woutb, bout, out, nullptr, 8192, 512, 512, 0, 0, 0);
}

// Round 5
// 177.720 us; speedup vs baseline: 5.1518x; 1.0507x over previous
//
#include <hip/hip_runtime.h>
#include <hip/hip_bf16.h>

typedef __hip_bfloat16 bf16;
typedef __bf16 bf16x8 __attribute__((ext_vector_type(8)));
typedef float f32x4 __attribute__((ext_vector_type(4)));

static_assert(sizeof(bf16) == 2, "bf16 must be 2 bytes");

#define NC 32   // chunks over L=1024
#define CH 32   // steps per chunk
#define X1TP_BSTRIDE (514L * 1024)  // padded x1^T per batch: rows -1..512

__device__ __forceinline__ float silu_f(float v) { return v / (1.0f + __expf(-v)); }

__device__ __forceinline__ void gload16(const bf16* g, bf16* l) {
  __builtin_amdgcn_global_load_lds((const __attribute__((address_space(1))) void*)g,
                                   (__attribute__((address_space(3))) void*)l,
                                   16, 0, 0);
}

template <int N> __device__ __forceinline__ void wait_vm() {
  if constexpr (N == 0)      asm volatile("s_waitcnt vmcnt(0)" ::: "memory");
  else if constexpr (N == 4) asm volatile("s_waitcnt vmcnt(4)" ::: "memory");
  else if constexpr (N == 6) asm volatile("s_waitcnt vmcnt(6)" ::: "memory");
  else static_assert(N == 0 || N == 4 || N == 6, "add case");
}

// ---------------- f32 -> bf16 convert (x) ----------------
__global__ __launch_bounds__(256) void f2b_kernel(const float* __restrict__ in,
                                                  bf16* __restrict__ out, int n) {
  int i = (blockIdx.x * 256 + threadIdx.x) * 4;
  if (i + 3 < n) {
    float4 v = *reinterpret_cast<const float4*>(in + i);
    ushort4 s;
    s.x = __builtin_bit_cast(unsigned short, __float2bfloat16(v.x));
    s.y = __builtin_bit_cast(unsigned short, __float2bfloat16(v.y));
    s.z = __builtin_bit_cast(unsigned short, __float2bfloat16(v.z));
    s.w = __builtin_bit_cast(unsigned short, __float2bfloat16(v.w));
    *reinterpret_cast<ushort4*>(out + i) = s;
  }
}

// ---------------- all weight converts + x1tp pad zeroing, one launch ----------------
__global__ __launch_bounds__(256) void prep_kernel(const float* __restrict__ W1,
                                                   const float* __restrict__ W2,
                                                   const float* __restrict__ Wout,
                                                   const float* __restrict__ Wdbc,
                                                   bf16* __restrict__ w1b, bf16* __restrict__ w2b,
                                                   bf16* __restrict__ woutb, bf16* __restrict__ wdbcb,
                                                   bf16* __restrict__ x1tp) {
  int gid = blockIdx.x * 256 + threadIdx.x;  // 65536 threads
  int i = gid * 4;
  auto cvt4 = [&](const float* src, bf16* dst) {
    float4 v = *reinterpret_cast<const float4*>(src + i);
    ushort4 s;
    s.x = __builtin_bit_cast(unsigned short, __float2bfloat16(v.x));
    s.y = __builtin_bit_cast(unsigned short, __float2bfloat16(v.y));
    s.z = __builtin_bit_cast(unsigned short, __float2bfloat16(v.z));
    s.w = __builtin_bit_cast(unsigned short, __float2bfloat16(v.w));
    *reinterpret_cast<ushort4*>(dst + i) = s;
  };
  cvt4(W1, w1b);
  cvt4(W2, w2b);
  cvt4(Wout, woutb);
  if (i < 64 * 512) cvt4(Wdbc, wdbcb);
  if (gid < 16384) {  // pad rows (d=-1 and d=512) for 8 batches
    int b = gid >> 11, rem = gid & 2047;
    int r = rem >> 10, ii = rem & 1023;
    x1tp[(long)b * X1TP_BSTRIDE + (long)r * (513 * 1024) + ii] = __float2bfloat16(0.f);
  }
}

// conv_w (1024x1024x3 f32, tap-minor) -> cw_split bf16 [o][k*1024 + i]
__global__ __launch_bounds__(256) void csplit_kernel(const float* __restrict__ cw,
                                                     bf16* __restrict__ cws) {
  long idx = (long)blockIdx.x * 256 + threadIdx.x;  // o*1024 + i
  int o = (int)(idx >> 10), i = (int)(idx & 1023);
  float a = cw[idx * 3], b = cw[idx * 3 + 1], c = cw[idx * 3 + 2];
  cws[(long)o * 3072 + i]        = __float2bfloat16(a);
  cws[(long)o * 3072 + 1024 + i] = __float2bfloat16(b);
  cws[(long)o * 3072 + 2048 + i] = __float2bfloat16(c);
}

// ---------------- MFMA GEMM, C[M,N] = A[M,K] * B[N,K]^T ----------------
// Counted-vmcnt 3-buffer pipeline (T4) + T2 swizzle + T1 XCD-bijective block swizzle.
// EPI: 2 = +bias[m], silu, bf16 -> outb + z*sOz, row-major [m][n]    (G3 conv)
//      3 = plain f32 out                                             (G4 dbc)
//      4 = +bias[n], f32 out                                         (G5 out)
//      5 = +bias[m], bf16 -> x1tp padded-transposed layout           (G1t)
//      6 = +bias[n], silu, bf16 row-major [m][n]                     (G2 gate)
// CONVB: B is virtual conv operand: row n, col kb*1024+i -> x1tp[z][(n+kb)*1024 + i]
template <int EPI, int BM, int BN, int CONVB, int GX, int GY>
__global__ __launch_bounds__(256) void gemm_nt(const bf16* __restrict__ A,
                                               const bf16* __restrict__ Bw,
                                               const float* __restrict__ bias,
                                               float* __restrict__ outf,
                                               bf16* __restrict__ outb,
                                               int M, int N, int K,
                                               long sAz, long sBz, long sOz) {
  constexpr int BK = 64;
  constexpr int MI = BM / 32, WNF = BN / 32;
  constexpr int APW = BM / 32, BPW = BN / 32;
  constexpr int IPW = APW + BPW;  // per-wave loads in flight per stage
  __shared__ __align__(16) bf16 As[3][BM * BK];
  __shared__ __align__(16) bf16 Bs[3][BN * BK];

  // T1: bijective XCD swizzle over flattened grid (gridDim.x % 8 == 0)
  const int bid = (blockIdx.x & 7) * ((int)gridDim.x >> 3) + (blockIdx.x >> 3);
  const int bx = bid & (GX - 1);
  const int by = (bid / GX) & (GY - 1);
  const int z  = bid / (GX * GY);

  const int tid = threadIdx.x;
  const int w = tid >> 6, l = tid & 63;
  const int wm = w >> 1, wn = w & 1;
  const int m0 = bx * BM, n0 = by * BN;
  const bf16* Ab = A + (long)z * sAz + (long)m0 * K;
  const bf16* Bb = Bw + (long)z * sBz;

  const int lrow = l >> 3;                       // row within 8-row stage group
  const int lcol = (((l & 7) ^ (l >> 3)) << 3);  // swizzled source col (elements)

  auto stage = [&](int buf, int k0) {
#pragma unroll
    for (int j = 0; j < APW; ++j) {
      int iss = w * APW + j;
      int row = iss * 8 + lrow;
      gload16(Ab + (long)row * K + k0 + lcol, &As[buf][iss * 512]);
    }
#pragma unroll
    for (int j = 0; j < BPW; ++j) {
      int iss = w * BPW + j;
      int row = iss * 8 + lrow;
      const bf16* src;
      if (CONVB) src = Bb + (long)(n0 + row + (k0 >> 10)) * 1024 + (k0 & 1023) + lcol;
      else       src = Bb + (long)(n0 + row) * K + k0 + lcol;
      gload16(src, &Bs[buf][iss * 512]);
    }
  };

  f32x4 acc[MI][WNF] = {};
  const int nt = K / BK;
  const int lr = l & 15;
  const int lko = (l >> 4) * 8;
  const int xorm = (lr & 7) << 3;

  stage(0, 0);
  stage(1, BK);
  for (int t = 0; t < nt; ++t) {
    const int cur = t % 3;
    if (t + 1 < nt) wait_vm<IPW>();   // stage(t) done; stage(t+1) still in flight
    else            wait_vm<0>();
    __builtin_amdgcn_s_barrier();
    __builtin_amdgcn_sched_barrier(0);
#pragma unroll
    for (int kk = 0; kk < 2; ++kk) {
      const int col = (lko + kk * 32) ^ xorm;
      bf16x8 af[MI], bfg[WNF];
#pragma unroll
      for (int mi = 0; mi < MI; ++mi)
        af[mi] = *reinterpret_cast<const bf16x8*>(&As[cur][(wm * (BM / 2) + mi * 16 + lr) * 64 + col]);
#pragma unroll
      for (int ni = 0; ni < WNF; ++ni)
        bfg[ni] = *reinterpret_cast<const bf16x8*>(&Bs[cur][(wn * (BN / 2) + ni * 16 + lr) * 64 + col]);
#pragma unroll
      for (int mi = 0; mi < MI; ++mi)
#pragma unroll
        for (int ni = 0; ni < WNF; ++ni)
          acc[mi][ni] = __builtin_amdgcn_mfma_f32_16x16x32_bf16(af[mi], bfg[ni], acc[mi][ni], 0, 0, 0);
    }
    __builtin_amdgcn_sched_barrier(0);
    __builtin_amdgcn_s_barrier();
    if (t + 2 < nt) stage((t + 2) % 3, (t + 2) * BK);  // overwrites buf last read at t-1: safe
  }

  // epilogue: D mapping col = lane&15, row = (lane>>4)*4 + j
  const int lq = l >> 4;
#pragma unroll
  for (int mi = 0; mi < MI; ++mi) {
#pragma unroll
    for (int ni = 0; ni < WNF; ++ni) {
#pragma unroll
      for (int j = 0; j < 4; ++j) {
        int m = m0 + wm * (BM / 2) + mi * 16 + lq * 4 + j;
        int n = n0 + wn * (BN / 2) + ni * 16 + lr;
        float v = acc[mi][ni][j];
        if (EPI == 2) {
          v += bias[m];
          (outb + (long)z * sOz)[(long)m * N + n] = __float2bfloat16(silu_f(v));
        } else if (EPI == 3) {
          outf[(long)m * N + n] = v;
        } else if (EPI == 4) {
          v += bias[n];
          outf[(long)m * N + n] = v;
        } else if (EPI == 5) {  // x1tp padded transposed
          v += bias[m];
          int b = n >> 10, li = n & 1023;
          outb[(long)b * X1TP_BSTRIDE + (long)(m + 1) * 1024 + li] = __float2bfloat16(v);
        } else {  // EPI 6: gate = silu(x@W2^T+b2), bf16 row-major
          v += bias[n];
          outb[(long)m * N + n] = __float2bfloat16(silu_f(v));
        }
      }
    }
  }
}

// ---------------- chunked selective scan (delta fused) ----------------
// Phase 1: per chunk, P = prod(dA), Q = local scan from h=0.
__global__ __launch_bounds__(256) void scan_p1(const bf16* __restrict__ u_bf,
                                               const float* __restrict__ dbc,
                                               const float* __restrict__ W_dt,
                                               const float* __restrict__ b_dt,
                                               const float* __restrict__ A_log,
                                               float* __restrict__ P,
                                               float* __restrict__ Q) {
  const int tid = threadIdx.x;
  const int d = blockIdx.x * 256 + tid;
  const int c = blockIdx.y, b = blockIdx.z;
  __shared__ float sD[CH][64];
  for (int i = tid; i < CH * 64; i += 256) {
    int tt = i >> 6, j = i & 63;
    sD[tt][j] = dbc[((long)b * 1024 + c * CH + tt) * 64 + j];
  }
  __syncthreads();
  float wdt[32];
#pragma unroll
  for (int r = 0; r < 32; r += 4) {
    float4 v = *reinterpret_cast<const float4*>(&W_dt[(long)d * 32 + r]);
    wdt[r] = v.x; wdt[r + 1] = v.y; wdt[r + 2] = v.z; wdt[r + 3] = v.w;
  }
  const float bd = b_dt[d];
  float Adn[16];
#pragma unroll
  for (int n = 0; n < 16; ++n) Adn[n] = -__expf(A_log[d * 16 + n]);
  float p[16], q[16];
#pragma unroll
  for (int n = 0; n < 16; ++n) { p[n] = 1.f; q[n] = 0.f; }
  const long rowb = (long)b * 1024 + c * CH;
  for (int tt = 0; tt < CH; ++tt) {
    float a = bd;
#pragma unroll
    for (int r = 0; r < 32; ++r) a = fmaf(sD[tt][r], wdt[r], a);
    float dv = fmaxf(a, 0.f) + log1pf(__expf(-fabsf(a)));  // softplus
    float uv = __bfloat162float(u_bf[(rowb + tt) * 512 + d]);
    float s = dv * uv;
#pragma unroll
    for (int n = 0; n < 16; ++n) {
      float dA = __expf(dv * Adn[n]);
      p[n] *= dA;
      q[n] = fmaf(dA, q[n], s * sD[tt][32 + n]);
    }
  }
  float* Pp = P + ((long)b * NC + c) * 8192 + (long)d * 16;
  float* Qp = Q + ((long)b * NC + c) * 8192 + (long)d * 16;
#pragma unroll
  for (int n4 = 0; n4 < 4; ++n4) {
    *reinterpret_cast<float4*>(Pp + n4 * 4) = make_float4(p[n4*4], p[n4*4+1], p[n4*4+2], p[n4*4+3]);
    *reinterpret_cast<float4*>(Qp + n4 * 4) = make_float4(q[n4*4], q[n4*4+1], q[n4*4+2], q[n4*4+3]);
  }
}

// Phase 2: scan over chunk summaries.
__global__ __launch_bounds__(256) void scan_p2(const float* __restrict__ P,
                                               const float* __restrict__ Q,
                                               float* __restrict__ Hin) {
  const int dn = blockIdx.x * 256 + threadIdx.x;
  const int b = blockIdx.y;
  float h = 0.f;
#pragma unroll 4
  for (int c = 0; c < NC; ++c) {
    long idx = ((long)b * NC + c) * 8192 + dn;
    Hin[idx] = h;
    h = fmaf(P[idx], h, Q[idx]);
  }
}

// Phase 3: re-scan chunk from Hin, emit z = y*gate + xres (bf16).
__global__ __launch_bounds__(256) void scan_p3(const bf16* __restrict__ u_bf,
                                               const float* __restrict__ dbc,
                                               const float* __restrict__ W_dt,
                                               const float* __restrict__ b_dt,
                                               const float* __restrict__ A_log,
                                               const float* __restrict__ Dp,
                                               const bf16* __restrict__ x2g,   // silu(x2), bf16
                                               const bf16* __restrict__ xres,  // x residual, bf16 (== zb)
                                               const float* __restrict__ Hin,
                                               bf16* __restrict__ zb) {
  const int tid = threadIdx.x;
  const int d = blockIdx.x * 256 + tid;
  const int c = blockIdx.y, b = blockIdx.z;
  __shared__ float sD[CH][64];
  for (int i = tid; i < CH * 64; i += 256) {
    int tt = i >> 6, j = i & 63;
    sD[tt][j] = dbc[((long)b * 1024 + c * CH + tt) * 64 + j];
  }
  __syncthreads();
  float wdt[32];
#pragma unroll
  for (int r = 0; r < 32; r += 4) {
    float4 v = *reinterpret_cast<const float4*>(&W_dt[(long)d * 32 + r]);
    wdt[r] = v.x; wdt[r + 1] = v.y; wdt[r + 2] = v.z; wdt[r + 3] = v.w;
  }
  const float bd = b_dt[d];
  float Adn[16];
#pragma unroll
  for (int n = 0; n < 16; ++n) Adn[n] = -__expf(A_log[d * 16 + n]);
  float h[16];
  const float* Hp = Hin + ((long)b * NC + c) * 8192 + (long)d * 16;
#pragma unroll
  for (int n4 = 0; n4 < 4; ++n4) {
    float4 v = *reinterpret_cast<const float4*>(Hp + n4 * 4);
    h[n4*4] = v.x; h[n4*4+1] = v.y; h[n4*4+2] = v.z; h[n4*4+3] = v.w;
  }
  const float Dpv = Dp[d];
  const long rowb = (long)b * 1024 + c * CH;
  for (int tt = 0; tt < CH; ++tt) {
    long off = (rowb + tt) * 512 + d;
    float a = bd;
#pragma unroll
    for (int r = 0; r < 32; ++r) a = fmaf(sD[tt][r], wdt[r], a);
    float dv = fmaxf(a, 0.f) + log1pf(__expf(-fabsf(a)));
    float uv = __bfloat162float(u_bf[off]);
    float s = dv * uv;
    float y = uv * Dpv;
#pragma unroll
    for (int n = 0; n < 16; ++n) {
      float dA = __expf(dv * Adn[n]);
      h[n] = fmaf(dA, h[n], s * sD[tt][32 + n]);
      y = fmaf(h[n], sD[tt][48 + n], y);
    }
    float gate = __bfloat162float(x2g[off]);
    float xv = __bfloat162float(xres[off]);
    zb[off] = __float2bfloat16(fmaf(y, gate, xv));
  }
}

extern "C" void kernel_launch(void* const* d_in, const int* in_sizes, int n_in,
                              void* d_out, int out_size, void* d_ws, size_t ws_size,
                              hipStream_t stream) {
  (void)in_sizes; (void)n_in; (void)out_size; (void)ws_size;
  const float* x    = (const float*)d_in[0];
  const float* W1   = (const float*)d_in[1];
  const float* b1   = (const float*)d_in[2];
  const float* W2   = (const float*)d_in[3];
  const float* b2   = (const float*)d_in[4];
  const float* Wout = (const float*)d_in[5];
  const float* bout = (const float*)d_in[6];
  const float* convw = (const float*)d_in[7];
  const float* convb = (const float*)d_in[8];
  const float* Wdbc = (const float*)d_in[9];
  const float* Wdt  = (const float*)d_in[10];
  const float* bdt  = (const float*)d_in[11];
  const float* Alog = (const float*)d_in[12];
  const float* Dp   = (const float*)d_in[13];
  float* out = (float*)d_out;

  char* ws = (char*)d_ws;
  size_t off = 0;
  auto alloc = [&](size_t bytes) { void* p = ws + off; off += (bytes + 255) & ~(size_t)255; return p; };
  bf16* xb     = (bf16*)alloc(8192L * 512 * 2);
  bf16* w1b    = (bf16*)alloc(512L * 512 * 2);
  bf16* w2b    = (bf16*)alloc(512L * 512 * 2);
  bf16* woutb  = (bf16*)alloc(512L * 512 * 2);
  bf16* wdbcb  = (bf16*)alloc(64L * 512 * 2);
  bf16* cws    = (bf16*)alloc(1024L * 3072 * 2);
  bf16* x1tp   = (bf16*)alloc(8L * X1TP_BSTRIDE * 2);
  bf16* x2g    = (bf16*)alloc(8192L * 512 * 2);
  bf16* x1s    = (bf16*)alloc(8192L * 512 * 2);
  float* dbc   = (float*)alloc(8192L * 64 * 4);
  float* P     = (float*)alloc(8L * NC * 8192 * 4);
  float* Q     = (float*)alloc(8L * NC * 8192 * 4);
  float* Hin   = (float*)alloc(8L * NC * 8192 * 4);
  bf16* zb = xb;  // xb dead (as x-copy) after G1t/G2; p3 reads xres==xb then overwrites

  f2b_kernel<<<8192 * 512 / 1024, 256, 0, stream>>>(x, xb, 8192 * 512);
  prep_kernel<<<256, 256, 0, stream>>>(W1, W2, Wout, Wdbc, w1b, w2b, woutb, wdbcb, x1tp);
  csplit_kernel<<<1024 * 1024 / 256, 256, 0, stream>>>(convw, cws);

  // G1t: x1^T = W1 @ x^T + b1[m] -> x1tp (padded, bf16)
  gemm_nt<5, 64, 128, 0, 8, 64><<<512, 256, 0, stream>>>(
      w1b, xb, b1, nullptr, x1tp, 512, 8192, 512, 0, 0, 0);
  // G2: gate = silu(x@W2^T + b2) -> x2g bf16
  gemm_nt<6, 64, 128, 0, 128, 4><<<512, 256, 0, stream>>>(
      xb, w2b, b2, nullptr, x2g, 8192, 512, 512, 0, 0, 0);
  // G3 (conv): silu(cw_split @ Bv^T + conv_b[o]) -> x1s bf16, per batch (z per XCD)
  gemm_nt<2, 64, 128, 1, 16, 4><<<512, 256, 0, stream>>>(
      cws, x1tp, convb, nullptr, x1s, 1024, 512, 3072, 0, X1TP_BSTRIDE, 1024L * 512);
  // G4: dbc = x1s @ Wdbc^T -> f32 (8192 x 64)
  gemm_nt<3, 64, 64, 0, 128, 1><<<128, 256, 0, stream>>>(
      x1s, wdbcb, nullptr, dbc, nullptr, 8192, 64, 512, 0, 0, 0);
  // chunked scan (delta fused into p1/p3)
  scan_p1<<<dim3(2, NC, 8), 256, 0, stream>>>(x1s, dbc, Wdt, bdt, Alog, P, Q);
  scan_p2<<<dim3(32, 8, 1), 256, 0, stream>>>(P, Q, Hin);
  scan_p3<<<dim3(2, NC, 8), 256, 0, stream>>>(x1s, dbc, Wdt, bdt, Alog, Dp, x2g, xb, Hin, zb);
  // G5: out = zb @ Wout^T + bout -> f32
  gemm_nt<4, 64, 128, 0, 128, 4><<<512, 256, 0, stream>>>(
      zb, woutb, bout, out, nullptr, 8192, 512, 512, 0, 0, 0);
}